// Round 1
// baseline (976.408 us; speedup 1.0000x reference)
//
#include <hip/hip_runtime.h>
#include <hip/hip_bf16.h>
#include <stdint.h>

#define D_DIM 4096
#define V_DIM 32000
#define B_SEQ 64
#define MAXC 2048

// ---- ws layout (float units) ----
#define HBUF_OFF   0u          // 64*4096 = 262144
#define LOGITS_OFF 262144u     // 64*32000 = 2048000
#define STATS_OFF  2310144u    // 128 (m,Z per row)
#define KTH_OFF    2310272u    // 64 u32
#define LK_OFF     2310336u    // 64 int
#define CCNT_OFF   2310400u    // 64 int
#define CKEY_OFF   2310464u    // 64*2048 u32
#define CIDX_OFF   2441536u    // 64*2048 int

__device__ __forceinline__ unsigned f2key(float x) {
    unsigned u = __float_as_uint(x);
    return (u & 0x80000000u) ? ~u : (u | 0x80000000u);
}
__device__ __forceinline__ float key2f(unsigned k) {
    unsigned u = (k & 0x80000000u) ? (k & 0x7FFFFFFFu) : ~k;
    return __uint_as_float(u);
}

// ---- gather last-token hidden rows into compact buffer ----
__global__ void k_gather(const float* __restrict__ hs, const int* __restrict__ lti,
                         float* __restrict__ h) {
    int b = blockIdx.x;
    size_t row = (size_t)lti[b];
    const float4* src = (const float4*)(hs + row * D_DIM);
    float4* dst = (float4*)(h + (size_t)b * D_DIM);
    for (int i = threadIdx.x; i < D_DIM / 4; i += blockDim.x) dst[i] = src[i];
}

// ---- fp32 GEMM: logits[b][v] = dot(h[b], emb[v]) / temp[b] ----
#define BN 128
#define BK 64
__global__ __launch_bounds__(256) void k_gemm(const float* __restrict__ h,
                                              const float* __restrict__ emb,
                                              const float* __restrict__ temps,
                                              float* __restrict__ logits) {
    __shared__ float sH[BK][68];    // transposed: sH[k][m]
    __shared__ float sE[BK][132];   // transposed: sE[k][n]
    const int vbase = blockIdx.x * BN;
    const int tid = threadIdx.x;
    const int tm = tid >> 4;        // 0..15 -> m0 = tm*4
    const int tn = tid & 15;        // 0..15 -> n0 = tn*8
    float acc[4][8];
#pragma unroll
    for (int i = 0; i < 4; ++i)
#pragma unroll
        for (int j = 0; j < 8; ++j) acc[i][j] = 0.f;

    for (int k0 = 0; k0 < D_DIM; k0 += BK) {
        // h tile: 64 rows x BK  (1024 float4)
        for (int qi = tid; qi < 64 * (BK / 4); qi += 256) {
            int r = qi >> 4, q = qi & 15;
            float4 v = *(const float4*)(h + (size_t)r * D_DIM + k0 + 4 * q);
            sH[4 * q + 0][r] = v.x; sH[4 * q + 1][r] = v.y;
            sH[4 * q + 2][r] = v.z; sH[4 * q + 3][r] = v.w;
        }
        // e tile: BN rows x BK  (2048 float4)
        for (int qi = tid; qi < BN * (BK / 4); qi += 256) {
            int r = qi >> 4, q = qi & 15;
            float4 v = *(const float4*)(emb + (size_t)(vbase + r) * D_DIM + k0 + 4 * q);
            sE[4 * q + 0][r] = v.x; sE[4 * q + 1][r] = v.y;
            sE[4 * q + 2][r] = v.z; sE[4 * q + 3][r] = v.w;
        }
        __syncthreads();
#pragma unroll 8
        for (int k = 0; k < BK; ++k) {
            float hreg[4], ereg[8];
            *(float4*)&hreg[0] = *(const float4*)&sH[k][tm * 4];
            *(float4*)&ereg[0] = *(const float4*)&sE[k][tn * 8];
            *(float4*)&ereg[4] = *(const float4*)&sE[k][tn * 8 + 4];
#pragma unroll
            for (int i = 0; i < 4; ++i)
#pragma unroll
                for (int j = 0; j < 8; ++j)
                    acc[i][j] = fmaf(hreg[i], ereg[j], acc[i][j]);
        }
        __syncthreads();
    }
#pragma unroll
    for (int i = 0; i < 4; ++i) {
        int bm = tm * 4 + i;
        float t = temps[bm];
        if (t < 1e-5f) t = 1.0f;
#pragma unroll
        for (int j = 0; j < 8; ++j)
            logits[(size_t)bm * V_DIM + vbase + tn * 8 + j] = acc[i][j] / t;
    }
}

// ---- per-row max + sum(exp) ----
__global__ void k_stats(const float* __restrict__ logits, float* __restrict__ stats) {
    int b = blockIdx.x;
    const float* lr = logits + (size_t)b * V_DIM;
    __shared__ float red[256];
    float mx = -3.4e38f;
    for (int v = threadIdx.x; v < V_DIM; v += 256) mx = fmaxf(mx, lr[v]);
    red[threadIdx.x] = mx; __syncthreads();
    for (int s = 128; s > 0; s >>= 1) {
        if (threadIdx.x < s) red[threadIdx.x] = fmaxf(red[threadIdx.x], red[threadIdx.x + s]);
        __syncthreads();
    }
    float m = red[0]; __syncthreads();
    float sum = 0.f;
    for (int v = threadIdx.x; v < V_DIM; v += 256) sum += expf(lr[v] - m);
    red[threadIdx.x] = sum; __syncthreads();
    for (int s = 128; s > 0; s >>= 1) {
        if (threadIdx.x < s) red[threadIdx.x] += red[threadIdx.x + s];
        __syncthreads();
    }
    if (threadIdx.x == 0) { stats[b * 2] = m; stats[b * 2 + 1] = red[0]; }
}

// ---- radix select k-th largest logit key per row (3 passes: 11/11/10 bits) ----
__global__ void k_select(const float* __restrict__ logits, const int* __restrict__ top_ks,
                         unsigned* __restrict__ kth, int* __restrict__ lk) {
    int b = blockIdx.x;
    const float* lr = logits + (size_t)b * V_DIM;
    int k = top_ks[b]; k = max(1, min(k, V_DIM));
    __shared__ unsigned hist[2048];
    __shared__ unsigned s_pref; __shared__ int s_kk; __shared__ unsigned s_above;
    if (threadIdx.x == 0) { s_pref = 0u; s_kk = k; s_above = 0u; }
    __syncthreads();
    const int shifts[3] = {21, 10, 0};
    const int nbits[3] = {11, 11, 10};
    unsigned pmask = 0u;
    for (int pass = 0; pass < 3; ++pass) {
        int nb = 1 << nbits[pass];
        for (int i = threadIdx.x; i < nb; i += blockDim.x) hist[i] = 0u;
        __syncthreads();
        unsigned pref = s_pref;
        for (int v = threadIdx.x; v < V_DIM; v += blockDim.x) {
            unsigned key = f2key(lr[v]);
            if ((key & pmask) == pref) {
                unsigned bk = (key >> shifts[pass]) & (unsigned)(nb - 1);
                atomicAdd(&hist[bk], 1u);
            }
        }
        __syncthreads();
        if (threadIdx.x == 0) {
            unsigned c = 0; int kk = s_kk; int sel = 0;
            for (int bk = nb - 1; bk >= 0; --bk) {
                if (c + hist[bk] >= (unsigned)kk) { sel = bk; break; }
                c += hist[bk];
            }
            s_pref = pref | ((unsigned)sel << shifts[pass]);
            s_kk = kk - (int)c;
            s_above += c;
            if (pass == 2) {
                lk[b] = (int)(s_above + hist[sel]);  // count(key >= kth key), ties included
                kth[b] = s_pref;
            }
        }
        __syncthreads();
        pmask |= ((unsigned)(nb - 1) << shifts[pass]);
    }
}

// ---- gather candidates (key >= kth) ----
__global__ void k_cand(const float* __restrict__ logits, const unsigned* __restrict__ kth,
                       unsigned* __restrict__ ckey, int* __restrict__ cidx,
                       int* __restrict__ ccnt) {
    int b = blockIdx.x;
    __shared__ int cnt;
    if (threadIdx.x == 0) cnt = 0;
    __syncthreads();
    unsigned Kth = kth[b];
    const float* lr = logits + (size_t)b * V_DIM;
    for (int v = threadIdx.x; v < V_DIM; v += blockDim.x) {
        unsigned key = f2key(lr[v]);
        if (key >= Kth) {
            int p = atomicAdd(&cnt, 1);
            if (p < MAXC) { ckey[b * MAXC + p] = key; cidx[b * MAXC + p] = v; }
        }
    }
    __syncthreads();
    if (threadIdx.x == 0) ccnt[b] = min(cnt, MAXC);
}

// ---- zero the probs output region ----
__global__ void k_zero(float4* __restrict__ p) {
    size_t i = (size_t)blockIdx.x * blockDim.x + threadIdx.x;
    p[i] = make_float4(0.f, 0.f, 0.f, 0.f);  // grid sized exactly
}

// ---- finalize: sort candidates, top-p prefix, sample, scatter probs ----
__global__ __launch_bounds__(1024) void k_final(const unsigned* __restrict__ ckey,
                                                const int* __restrict__ cidx,
                                                const int* __restrict__ ccnt,
                                                const float* __restrict__ stats,
                                                const float* __restrict__ top_ps,
                                                const float* __restrict__ uu,
                                                float* __restrict__ out_tok,
                                                float* __restrict__ out_probs) {
    int b = blockIdx.x;
    int n = min(ccnt[b], MAXC);
    __shared__ unsigned long long sk[MAXC];
    __shared__ float sp[MAXC];
    __shared__ int sL; __shared__ float sTot; __shared__ int sTok;
    for (int i = threadIdx.x; i < MAXC; i += blockDim.x) {
        if (i < n) {
            unsigned key = ckey[b * MAXC + i];
            sk[i] = (((unsigned long long)(~key)) << 32) | (unsigned)cidx[b * MAXC + i];
        } else sk[i] = 0xFFFFFFFFFFFFFFFFULL;
    }
    __syncthreads();
    // bitonic ascending sort: key desc (via ~key), idx asc tiebreak
    for (unsigned size = 2; size <= MAXC; size <<= 1) {
        for (unsigned stride = size >> 1; stride > 0; stride >>= 1) {
            for (unsigned i = threadIdx.x; i < MAXC; i += blockDim.x) {
                unsigned j = i ^ stride;
                if (j > i) {
                    unsigned long long a = sk[i], c = sk[j];
                    bool up = ((i & size) == 0);
                    if (up ? (a > c) : (a < c)) { sk[i] = c; sk[j] = a; }
                }
            }
            __syncthreads();
        }
    }
    float m = stats[b * 2], Z = stats[b * 2 + 1];
    for (int i = threadIdx.x; i < n; i += blockDim.x) {
        unsigned key = ~(unsigned)(sk[i] >> 32);
        float l = key2f(key);
        sp[i] = expf(l - m) / Z;
    }
    __syncthreads();
    if (threadIdx.x == 0) {
        float top_p = top_ps[b];
        bool keepall = (top_p >= 1.0f - 1e-5f);
        // top-p prefix: keep i iff fl(cum[i]-f[i]) <= top_p  (np-sequential fp32)
        float c = 0.f; int L = n;
        for (int i = 0; i < n; ++i) {
            float cum = c + sp[i];
            float lhs = cum - sp[i];
            if (!keepall && !(lhs <= top_p)) { L = i; break; }
            c = cum;
        }
        float total = c;
        float target = uu[b] * total;
        // inverse CDF: j = first i with cdf[i] >= target
        float c2 = 0.f; int j = L - 1;
        for (int i = 0; i < L; ++i) {
            c2 += sp[i];
            if (!(c2 < target)) { j = i; break; }
        }
        sL = L; sTot = total;
        sTok = (int)(sk[j] & 0xFFFFFFFFULL);
        out_tok[b] = (float)sTok;
    }
    __syncthreads();
    int L = sL; float total = sTot;
    for (int i = threadIdx.x; i < L; i += blockDim.x) {
        int v = (int)(sk[i] & 0xFFFFFFFFULL);
        out_probs[(size_t)b * V_DIM + v] = sp[i] / total;
    }
}

extern "C" void kernel_launch(void* const* d_in, const int* in_sizes, int n_in,
                              void* d_out, int out_size, void* d_ws, size_t ws_size,
                              hipStream_t stream) {
    const float* hs    = (const float*)d_in[0];
    const float* emb   = (const float*)d_in[1];
    const float* temps = (const float*)d_in[2];
    const float* tps   = (const float*)d_in[3];
    const float* uu    = (const float*)d_in[4];
    const int*   lti   = (const int*)d_in[5];
    const int*   tks   = (const int*)d_in[6];

    float* ws = (float*)d_ws;
    float*    hbuf   = ws + HBUF_OFF;
    float*    logits = ws + LOGITS_OFF;
    float*    stats  = ws + STATS_OFF;
    unsigned* kth    = (unsigned*)(ws + KTH_OFF);
    int*      lk     = (int*)(ws + LK_OFF);
    int*      ccnt   = (int*)(ws + CCNT_OFF);
    unsigned* ckey   = (unsigned*)(ws + CKEY_OFF);
    int*      cidx   = (int*)(ws + CIDX_OFF);

    float* out_tok   = (float*)d_out;        // tokens as float32 values
    float* out_probs = (float*)d_out + B_SEQ;

    k_gather<<<B_SEQ, 256, 0, stream>>>(hs, lti, hbuf);
    k_gemm<<<V_DIM / BN, 256, 0, stream>>>(hbuf, emb, temps, logits);
    k_zero<<<(B_SEQ * V_DIM / 4) / 256, 256, 0, stream>>>((float4*)out_probs);
    k_stats<<<B_SEQ, 256, 0, stream>>>(logits, stats);
    k_select<<<B_SEQ, 256, 0, stream>>>(logits, tks, kth, lk);
    k_cand<<<B_SEQ, 256, 0, stream>>>(logits, kth, ckey, cidx, ccnt);
    k_final<<<B_SEQ, 1024, 0, stream>>>(ckey, cidx, ccnt, stats, tps, uu,
                                        out_tok, out_probs);
}

// Round 4
// 447.370 us; speedup vs baseline: 2.1826x; 2.1826x over previous
//
#include <hip/hip_runtime.h>
#include <stdint.h>

#define D_DIM 4096
#define V_DIM 32000
#define B_SEQ 64
#define MAXC 2048

typedef __attribute__((ext_vector_type(8))) short short8;
typedef __attribute__((ext_vector_type(4))) float f32x4;

// ---- ws layout (float units) ----
// each limb array: 64*4096 ushorts = 512 KiB = 131072 floats
#define H1_OFF     0u
#define H2_OFF     131072u
#define H3_OFF     262144u
#define LOGITS_OFF 393216u   // 64*32000 floats -> total 2,441,216 floats (~9.77 MB)

__device__ __forceinline__ unsigned f2key(float x) {
    unsigned u = __float_as_uint(x);
    return (u & 0x80000000u) ? ~u : (u | 0x80000000u);
}
__device__ __forceinline__ float key2f(unsigned k) {
    unsigned u = (k & 0x80000000u) ? (k & 0x7FFFFFFFu) : ~k;
    return __uint_as_float(u);
}
// round-half-up fp32 -> bf16 (symmetric residual, no coherent bias)
__device__ __forceinline__ ushort rhu16(float x) {
    unsigned u = __float_as_uint(x);
    return (ushort)((u + 0x8000u) >> 16);
}
__device__ __forceinline__ float bf2f(ushort h) {
    return __uint_as_float((unsigned)h << 16);
}

// ---- gather last-token rows + split into 3 bf16 limbs ----
__global__ void k_prep(const float* __restrict__ hs, const int* __restrict__ lti,
                       ushort* __restrict__ h1, ushort* __restrict__ h2,
                       ushort* __restrict__ h3) {
    int b = blockIdx.x;
    const float4* src = (const float4*)(hs + (size_t)lti[b] * D_DIM);
    ushort4* d1 = (ushort4*)(h1 + (size_t)b * D_DIM);
    ushort4* d2 = (ushort4*)(h2 + (size_t)b * D_DIM);
    ushort4* d3 = (ushort4*)(h3 + (size_t)b * D_DIM);
    for (int i = threadIdx.x; i < D_DIM / 4; i += blockDim.x) {
        float4 v = src[i];
        float x[4] = {v.x, v.y, v.z, v.w};
        ushort l1[4], l2[4], l3[4];
#pragma unroll
        for (int j = 0; j < 4; ++j) {
            l1[j] = rhu16(x[j]);
            float r1 = x[j] - bf2f(l1[j]);
            l2[j] = rhu16(r1);
            float r2 = r1 - bf2f(l2[j]);
            l3[j] = rhu16(r2);
        }
        d1[i] = make_ushort4(l1[0], l1[1], l1[2], l1[3]);
        d2[i] = make_ushort4(l2[0], l2[1], l2[2], l2[3]);
        d3[i] = make_ushort4(l3[0], l3[1], l3[2], l3[3]);
    }
}

// ---- MFMA GEMM, 3-limb bf16 x 3-limb bf16, 6 products (~fp32 accuracy) ----
__global__ __launch_bounds__(256, 2) void k_gemm(const ushort* __restrict__ h1,
                                                 const ushort* __restrict__ h2,
                                                 const ushort* __restrict__ h3,
                                                 const float* __restrict__ emb,
                                                 const float* __restrict__ temps,
                                                 float* __restrict__ logits) {
    __shared__ __align__(16) ushort sA1[64 * 64];  // [row][k], XOR-swizzled 16B slots
    __shared__ __align__(16) ushort sA2[64 * 64];
    __shared__ __align__(16) ushort sA3[64 * 64];
    const int tid = threadIdx.x;
    const int w = tid >> 6, lane = tid & 63, lrow = lane & 15, q = lane >> 4;
    const int vrow = blockIdx.x * 64 + w * 16 + lrow;

    f32x4 acc[4];
#pragma unroll
    for (int mf = 0; mf < 4; ++mf)
#pragma unroll
        for (int r = 0; r < 4; ++r) acc[mf][r] = 0.f;

    // staging coords: thread t stages row = t>>2, 16 elems at (t&3)*16, all 3 limbs
    const int srow = tid >> 2;
    const int skb = (tid & 3) * 16;
    const unsigned swz = ((unsigned)(srow & 7)) << 4;
    const unsigned wrb = (unsigned)srow * 128u + (unsigned)(tid & 3) * 32u;
    const size_t gsoff = (size_t)srow * D_DIM + skb;

    uint4 p10, p11, p20, p21, p30, p31;
    {
        const ushort* g1 = h1 + gsoff;
        const ushort* g2 = h2 + gsoff;
        const ushort* g3 = h3 + gsoff;
        p10 = *(const uint4*)g1; p11 = *(const uint4*)(g1 + 8);
        p20 = *(const uint4*)g2; p21 = *(const uint4*)(g2 + 8);
        p30 = *(const uint4*)g3; p31 = *(const uint4*)(g3 + 8);
    }

    for (int k0 = 0; k0 < D_DIM; k0 += 64) {
        __syncthreads();   // previous iteration's LDS reads done
        *(uint4*)((char*)sA1 + ((wrb + 0u) ^ swz)) = p10;
        *(uint4*)((char*)sA1 + ((wrb + 16u) ^ swz)) = p11;
        *(uint4*)((char*)sA2 + ((wrb + 0u) ^ swz)) = p20;
        *(uint4*)((char*)sA2 + ((wrb + 16u) ^ swz)) = p21;
        *(uint4*)((char*)sA3 + ((wrb + 0u) ^ swz)) = p30;
        *(uint4*)((char*)sA3 + ((wrb + 16u) ^ swz)) = p31;
        __syncthreads();   // stores visible
        if (k0 + 64 < D_DIM) {  // prefetch next A-stage (hides under MFMA)
            const ushort* g1 = h1 + gsoff + k0 + 64;
            const ushort* g2 = h2 + gsoff + k0 + 64;
            const ushort* g3 = h3 + gsoff + k0 + 64;
            p10 = *(const uint4*)g1; p11 = *(const uint4*)(g1 + 8);
            p20 = *(const uint4*)g2; p21 = *(const uint4*)(g2 + 8);
            p30 = *(const uint4*)g3; p31 = *(const uint4*)(g3 + 8);
        }
#pragma unroll
        for (int s = 0; s < 2; ++s) {
            // B fragment: lane reads 8 contiguous k of its emb row; 3-limb split
            const float* bp = emb + (size_t)vrow * D_DIM + k0 + s * 32 + q * 8;
            float4 bv0 = *(const float4*)bp;
            float4 bv1 = *(const float4*)(bp + 4);
            float xf[8] = {bv0.x, bv0.y, bv0.z, bv0.w, bv1.x, bv1.y, bv1.z, bv1.w};
            short8 vb1, vb2, vb3;
#pragma unroll
            for (int j = 0; j < 8; ++j) {
                ushort u1 = rhu16(xf[j]);
                float r1 = xf[j] - bf2f(u1);
                ushort u2 = rhu16(r1);
                float r2 = r1 - bf2f(u2);
                ushort u3 = rhu16(r2);
                vb1[j] = (short)u1; vb2[j] = (short)u2; vb3[j] = (short)u3;
            }
#pragma unroll
            for (int mf = 0; mf < 4; ++mf) {
                int row = mf * 16 + lrow;
                unsigned off = ((unsigned)row * 128u + (unsigned)(s * 64 + q * 16))
                               ^ (((unsigned)(row & 7)) << 4);
                short8 a1 = *(const short8*)((const char*)sA1 + off);
                short8 a2 = *(const short8*)((const char*)sA2 + off);
                short8 a3 = *(const short8*)((const char*)sA3 + off);
                acc[mf] = __builtin_amdgcn_mfma_f32_16x16x32_bf16(a1, vb1, acc[mf], 0, 0, 0);
                acc[mf] = __builtin_amdgcn_mfma_f32_16x16x32_bf16(a1, vb2, acc[mf], 0, 0, 0);
                acc[mf] = __builtin_amdgcn_mfma_f32_16x16x32_bf16(a2, vb1, acc[mf], 0, 0, 0);
                acc[mf] = __builtin_amdgcn_mfma_f32_16x16x32_bf16(a2, vb2, acc[mf], 0, 0, 0);
                acc[mf] = __builtin_amdgcn_mfma_f32_16x16x32_bf16(a1, vb3, acc[mf], 0, 0, 0);
                acc[mf] = __builtin_amdgcn_mfma_f32_16x16x32_bf16(a3, vb1, acc[mf], 0, 0, 0);
            }
        }
    }
    // epilogue: C col = lane&15 (vrow), row = mf*16 + q*4 + r (= batch m)
#pragma unroll
    for (int mf = 0; mf < 4; ++mf)
#pragma unroll
        for (int r = 0; r < 4; ++r) {
            int m = mf * 16 + q * 4 + r;
            float t = temps[m];
            if (t < 1e-5f) t = 1.0f;
            logits[(size_t)m * V_DIM + vrow] = acc[mf][r] / t;
        }
}

// ---- zero probs region ----
__global__ void k_zero(float4* __restrict__ p) {
    size_t i = (size_t)blockIdx.x * blockDim.x + threadIdx.x;
    p[i] = make_float4(0.f, 0.f, 0.f, 0.f);
}

// ---- fused per-row: max/Z + radix-select + gather + sort + top-p + sample ----
__global__ __launch_bounds__(512) void k_sample(const float* __restrict__ logits,
                                                const int* __restrict__ tks,
                                                const float* __restrict__ tps,
                                                const float* __restrict__ uu,
                                                float* __restrict__ out_tok,
                                                float* __restrict__ out_probs) {
    const int b = blockIdx.x, t = threadIdx.x;
    const float* lr = logits + (size_t)b * V_DIM;
    __shared__ unsigned hist[2048];
    __shared__ unsigned redu[512];
    __shared__ float redf[512];
    __shared__ unsigned long long cand[MAXC];
    __shared__ float sp[MAXC];
    __shared__ unsigned s_sel1, s_ab1, s_thr, s_nc, s_ab2;
    __shared__ float s_m, s_Z, s_tot;
    __shared__ int s_cnt, s_L, s_tok;

    int k = tks[b];
    if (k < 1) k = 1;
    if (k > V_DIM) k = V_DIM;

    // ---- pass A: max + top-11-bit histogram ----
    for (int i = t; i < 2048; i += 512) hist[i] = 0u;
    __syncthreads();
    unsigned km = 0u;
    for (int v = t; v < V_DIM; v += 512) {
        unsigned key = f2key(lr[v]);
        km = max(km, key);
        atomicAdd(&hist[key >> 21], 1u);
    }
    redu[t] = km;
    __syncthreads();
    for (int s = 256; s > 0; s >>= 1) {
        if (t < s) redu[t] = max(redu[t], redu[t + s]);
        __syncthreads();
    }
    if (t == 0) s_m = key2f(redu[0]);
    __syncthreads();
    float m = s_m;
    redu[t] = hist[4 * t] + hist[4 * t + 1] + hist[4 * t + 2] + hist[4 * t + 3];
    __syncthreads();
    if (t == 0) {
        unsigned acc = 0; int g = 511;
        for (; g > 0; --g) { unsigned s4 = redu[g]; if (acc + s4 >= (unsigned)k) break; acc += s4; }
        int sel = 4 * g;
        for (int bk = 4 * g + 3; bk >= 4 * g; --bk) {
            unsigned h = hist[bk];
            if (acc + h >= (unsigned)k) { sel = bk; break; }
            acc += h;
        }
        s_sel1 = (unsigned)sel; s_ab1 = acc;
    }
    __syncthreads();
    unsigned sel1 = s_sel1, ab1 = s_ab1;

    // ---- pass B: exp-sum + mid-11-bit histogram within sel1 ----
    for (int i = t; i < 2048; i += 512) hist[i] = 0u;
    __syncthreads();
    float es = 0.f;
    for (int v = t; v < V_DIM; v += 512) {
        float f = lr[v];
        es += expf(f - m);
        unsigned key = f2key(f);
        if ((key >> 21) == sel1) atomicAdd(&hist[(key >> 10) & 2047u], 1u);
    }
    redf[t] = es;
    __syncthreads();
    for (int s = 256; s > 0; s >>= 1) {
        if (t < s) redf[t] += redf[t + s];
        __syncthreads();
    }
    if (t == 0) s_Z = redf[0];
    __syncthreads();
    redu[t] = hist[4 * t] + hist[4 * t + 1] + hist[4 * t + 2] + hist[4 * t + 3];
    __syncthreads();
    if (t == 0) {
        unsigned kk = (unsigned)k - ab1;
        unsigned acc = 0; int g = 511;
        for (; g > 0; --g) { unsigned s4 = redu[g]; if (acc + s4 >= kk) break; acc += s4; }
        int sel = 4 * g;
        for (int bk = 4 * g + 3; bk >= 4 * g; --bk) {
            unsigned h = hist[bk];
            if (acc + h >= kk) { sel = bk; break; }
            acc += h;
        }
        s_ab2 = ab1 + acc;
        s_thr = (sel1 << 21) | ((unsigned)sel << 10);
        s_nc = ab1 + acc + hist[sel];
    }
    __syncthreads();
    unsigned thr = s_thr;

    // ---- rare pass C: exact kth key if 22-bit bin too fat ----
    if (s_nc > (unsigned)MAXC) {
        for (int i = t; i < 1024; i += 512) hist[i] = 0u;
        __syncthreads();
        for (int v = t; v < V_DIM; v += 512) {
            unsigned key = f2key(lr[v]);
            if ((key & 0xFFFFFC00u) == thr) atomicAdd(&hist[key & 1023u], 1u);
        }
        __syncthreads();
        if (t == 0) {
            unsigned kk = (unsigned)k - s_ab2;
            unsigned acc = 0; int sel = 0;
            for (int bk = 1023; bk >= 0; --bk) {
                unsigned h = hist[bk];
                if (acc + h >= kk) { sel = bk; break; }
                acc += h;
            }
            s_thr = thr | (unsigned)sel;
        }
        __syncthreads();
        thr = s_thr;
    }

    // ---- gather candidates (key >= thr: superset of top-k incl. ties) ----
    if (t == 0) s_cnt = 0;
    for (int i = t; i < MAXC; i += 512) cand[i] = 0xFFFFFFFFFFFFFFFFULL;
    __syncthreads();
    for (int v = t; v < V_DIM; v += 512) {
        unsigned key = f2key(lr[v]);
        if (key >= thr) {
            int p = atomicAdd(&s_cnt, 1);
            if (p < MAXC) cand[p] = (((unsigned long long)(~key)) << 32) | (unsigned)v;
        }
    }
    __syncthreads();
    int n = s_cnt; if (n > MAXC) n = MAXC;

    // ---- bitonic sort (key desc, idx asc) ----
    for (unsigned size = 2; size <= MAXC; size <<= 1)
        for (unsigned stride = size >> 1; stride > 0; stride >>= 1) {
            for (unsigned i = t; i < MAXC; i += 512) {
                unsigned j = i ^ stride;
                if (j > i) {
                    unsigned long long a = cand[i], c = cand[j];
                    bool up = ((i & size) == 0);
                    if (up ? (a > c) : (a < c)) { cand[i] = c; cand[j] = a; }
                }
            }
            __syncthreads();
        }
    float Z = s_Z;
    for (int i = t; i < n; i += 512) {
        unsigned key = ~(unsigned)(cand[i] >> 32);
        sp[i] = expf(key2f(key) - m) / Z;
    }
    __syncthreads();

    if (t == 0) {
        unsigned kthkey = ~(unsigned)(cand[k - 1] >> 32);
        float top_p = tps[b];
        bool keepall = (top_p >= 1.0f - 1e-5f);
        float c = 0.f; int L = 0;
        for (int i = 0; i < n; ++i) {
            unsigned key = ~(unsigned)(cand[i] >> 32);
            if (key < kthkey) break;               // top-k cut (ties kept)
            float cum = c + sp[i];
            float lhs = cum - sp[i];               // np-sequential rounding order
            if (!keepall && !(lhs <= top_p)) break;
            c = cum; L = i + 1;
        }
        float total = c;
        float target = uu[b] * total;
        float c2 = 0.f; int j = L - 1;
        for (int i = 0; i < L; ++i) {
            c2 += sp[i];
            if (!(c2 < target)) { j = i; break; }
        }
        s_tok = (int)(cand[j] & 0xFFFFFFFFULL);
        s_L = L; s_tot = total;
        out_tok[b] = (float)s_tok;
    }
    __syncthreads();
    int L = s_L; float total = s_tot;
    for (int i = t; i < L; i += 512) {
        unsigned v = (unsigned)(cand[i] & 0xFFFFFFFFULL);
        out_probs[(size_t)b * V_DIM + v] = sp[i] / total;
    }
}

extern "C" void kernel_launch(void* const* d_in, const int* in_sizes, int n_in,
                              void* d_out, int out_size, void* d_ws, size_t ws_size,
                              hipStream_t stream) {
    const float* hs    = (const float*)d_in[0];
    const float* emb   = (const float*)d_in[1];
    const float* temps = (const float*)d_in[2];
    const float* tps   = (const float*)d_in[3];
    const float* uu    = (const float*)d_in[4];
    const int*   lti   = (const int*)d_in[5];
    const int*   tks   = (const int*)d_in[6];

    float* ws = (float*)d_ws;
    ushort* h1 = (ushort*)(ws + H1_OFF);
    ushort* h2 = (ushort*)(ws + H2_OFF);
    ushort* h3 = (ushort*)(ws + H3_OFF);
    float* logits = ws + LOGITS_OFF;

    float* out_tok   = (float*)d_out;
    float* out_probs = (float*)d_out + B_SEQ;

    k_prep<<<B_SEQ, 256, 0, stream>>>(hs, lti, h1, h2, h3);
    k_gemm<<<V_DIM / 64, 256, 0, stream>>>(h1, h2, h3, emb, temps, logits);
    k_zero<<<(B_SEQ * V_DIM / 4) / 256, 256, 0, stream>>>((float4*)out_probs);
    k_sample<<<B_SEQ, 512, 0, stream>>>(logits, tks, tps, uu, out_tok, out_probs);
}